// Round 16
// baseline (75.081 us; speedup 1.0000x reference)
//
#include <hip/hip_runtime.h>

typedef __attribute__((ext_vector_type(8))) short svec8;
typedef __attribute__((ext_vector_type(4))) float fvec4;

#define NB    4096
#define NN    6
#define FF    512
#define CC    256
#define KFULL 1024
#define MROWS (NB*NN)                 // 24576
#define AD_HALF ((size_t)MROWS*CC)    // 6291456 elements
#define NTOT  (NB*NN*NN)              // 147456

// LDS map (k_gemm_fused):
//  K-loop : Abuf0@0 Abuf1@12288 (12KB each) | Bbuf0@24576 Bbuf1@57344 (32KB each) (end 90112)
//  Tail   : Alds@0 (96 rows x 528B = 50688) | Dlds@50688 (end 101376) | red@101376 (4KB)
#define ABUF_STRIDE 12288
#define BOFF        24576
#define BBUF_STRIDE 32768
#define DOFF        50688
#define REDOFF      101376
#define ROWB        528
#define LDS_BYTES   105472

#define GLOAD16(gp, lp) __builtin_amdgcn_global_load_lds(                      \
    (const __attribute__((address_space(1))) unsigned int*)(gp),               \
    (__attribute__((address_space(3))) unsigned int*)(lp), 16, 0, 0)

__device__ __forceinline__ unsigned short f2bf(float f) {
    unsigned u = __float_as_uint(f);
    u += 0x7FFFu + ((u >> 16) & 1u);   // round-to-nearest-even
    return (unsigned short)(u >> 16);
}
__device__ __forceinline__ float bf2f(unsigned short h) {
    return __uint_as_float(((unsigned)h) << 16);
}
__device__ __forceinline__ svec8 cvt8(fvec4 lo, fvec4 hi) {
    svec8 v;
    v[0] = (short)f2bf(lo[0]); v[1] = (short)f2bf(lo[1]);
    v[2] = (short)f2bf(lo[2]); v[3] = (short)f2bf(lo[3]);
    v[4] = (short)f2bf(hi[0]); v[5] = (short)f2bf(hi[1]);
    v[6] = (short)f2bf(hi[2]); v[7] = (short)f2bf(hi[3]);
    return v;
}

// ---------------- kernel 0: conv_w fp32->bf16 + zero stats ----------------
__global__ __launch_bounds__(256) void k_pre(const float* __restrict__ w,
                                             unsigned short* __restrict__ wbf,
                                             float* __restrict__ stats) {
    int g = blockIdx.x * 256 + threadIdx.x;   // grid 256 -> 65536 vec4 chunks
    fvec4 v = *(const fvec4*)(w + (size_t)g * 4);
    unsigned long long pk = (unsigned long long)f2bf(v[0])
                          | ((unsigned long long)f2bf(v[1]) << 16)
                          | ((unsigned long long)f2bf(v[2]) << 32)
                          | ((unsigned long long)f2bf(v[3]) << 48);
    *(unsigned long long*)(wbf + (size_t)g * 4) = pk;
    if (g < 512) stats[g] = 0.f;
}

// ---------------- kernel 1: GEMM both halves + in-LDS stats tail ----------------
// grid 256 x 768 thr (12 waves = 3/SIMD, 1 block/CU). Block owns rows
// [mtile*96,+96) = 16 b-groups. Pass s=0: A-half, s=1: D-half. Dbuf K-loop
// (R11, proven). Tail: acc -> LDS bf16; AD global-write coalesced from LDS
// (stays in flight); stats computed from LDS (no L2 round-trip, no drain).
__global__ __launch_bounds__(768, 1) void k_gemm_fused(
        const float* __restrict__ x,
        const unsigned short* __restrict__ wbf,
        const float* __restrict__ conv_b,
        unsigned short* __restrict__ AD,
        float* __restrict__ stats) {
    __shared__ __align__(16) char lds[LDS_BYTES];
    const int tid = threadIdx.x;
    const int mtile = blockIdx.x;               // 0..255
    const int wv = tid >> 6;
    const int cg = wv & 3;                      // col-group: 64 cols
    const int rh = wv >> 2;                     // row-group: 32 rows

    // A staging: 768 16B-chunks, exactly one per thread. row 0..95, slot 0..7
    const int arow = tid >> 3, slot = tid & 7;
    const int a_off = arow * 128 + ((slot * 16) ^ ((arow & 7) << 4));

    // B staging: 2048 chunks; i=0,1 all threads, i=2 only tid<512
    int bxs[3], brow[3], bdoff[3];
#pragma unroll
    for (int i = 0; i < 3; ++i) {
        int ci = i * 768 + tid;
        brow[i] = ci >> 3;
        bxs[i] = ((ci & 7) ^ (brow[i] & 7)) << 3;
        bdoff[i] = i * 12288 + wv * 1024;       // wave-uniform base
    }
    const bool has_b2 = (tid < 512);

    // fragment LDS offsets
    const int l = tid & 63;
    const int lrow = l & 15;
    const int lk = l >> 4;
    int abase[2], bbase[2];
#pragma unroll
    for (int ks = 0; ks < 2; ++ks) {
        int xr = (ks * 64 + lk * 16) ^ ((lrow & 7) << 4);
        abase[ks] = (rh * 32 + lrow) * 128 + xr;
        bbase[ks] = BOFF + (cg * 64 + lrow) * 128 + xr;
    }

    const fvec4 vzero = {0.f, 0.f, 0.f, 0.f};
    fvec4 accA[2][4], accD[2][4];
#pragma unroll
    for (int mi = 0; mi < 2; ++mi)
#pragma unroll
        for (int ni = 0; ni < 4; ++ni) { accA[mi][ni] = vzero; accD[mi][ni] = vzero; }

#pragma unroll
    for (int s = 0; s < 2; ++s) {
        fvec4 (&acc)[2][4] = s ? accD : accA;

        // per-pass global A address (1 row-chunk per thread)
        int m0 = mtile * 96 + arow, b0 = m0 / 6, j0 = m0 - b0 * 6;
        const float* aptr = x + ((size_t)((b0 * 2 + s) * 6 + j0)) * FF + slot * 8;

        const unsigned short* bsrc[3];
#pragma unroll
        for (int i = 0; i < 3; ++i)
            bsrc[i] = wbf + (size_t)brow[i] * KFULL + s * FF + bxs[i];

        // ---- prologue: stage tile kt=0 into buf0 ----
        GLOAD16(bsrc[0], lds + BOFF + bdoff[0]);
        GLOAD16(bsrc[1], lds + BOFF + bdoff[1]);
        if (has_b2) GLOAD16(bsrc[2], lds + BOFF + bdoff[2]);
        {
            fvec4 lo = *(const fvec4*)aptr, hi = *(const fvec4*)(aptr + 4);
            *(svec8*)(lds + a_off) = cvt8(lo, hi);
        }
        __syncthreads();

#pragma unroll
        for (int kt = 0; kt < 8; ++kt) {
            const int cur = kt & 1, nxt = cur ^ 1;
            fvec4 nlo, nhi;
            // 1) issue next-tile loads BEFORE compute
            if (kt < 7) {
                GLOAD16(bsrc[0] + (kt + 1) * 64, lds + BOFF + nxt * BBUF_STRIDE + bdoff[0]);
                GLOAD16(bsrc[1] + (kt + 1) * 64, lds + BOFF + nxt * BBUF_STRIDE + bdoff[1]);
                if (has_b2)
                    GLOAD16(bsrc[2] + (kt + 1) * 64, lds + BOFF + nxt * BBUF_STRIDE + bdoff[2]);
                const float* p = aptr + (kt + 1) * 64;
                nlo = *(const fvec4*)p; nhi = *(const fvec4*)(p + 4);
            }
            // 2) MFMA on current buffers
#pragma unroll
            for (int ks = 0; ks < 2; ++ks) {
                svec8 af[2], bfr[4];
#pragma unroll
                for (int mi = 0; mi < 2; ++mi)
                    af[mi] = *(const svec8*)(lds + cur * ABUF_STRIDE + abase[ks] + mi * 2048);
#pragma unroll
                for (int ni = 0; ni < 4; ++ni)
                    bfr[ni] = *(const svec8*)(lds + cur * BBUF_STRIDE + bbase[ks] + ni * 2048);
#pragma unroll
                for (int mi = 0; mi < 2; ++mi)
#pragma unroll
                    for (int ni = 0; ni < 4; ++ni)
                        acc[mi][ni] = __builtin_amdgcn_mfma_f32_16x16x32_bf16(
                            af[mi], bfr[ni], acc[mi][ni], 0, 0, 0);
            }
            // 3) write next A tile (reg load covered by MFMA phase)
            if (kt < 7)
                *(svec8*)(lds + nxt * ABUF_STRIDE + a_off) = cvt8(nlo, nhi);
            __syncthreads();
        }
        // (no per-pass epilogue; acc stays in regs. Loop-end barrier protects
        //  next pass's buf0 prologue writes: buf0 reads finished at kt=6.)
    }

    // ---- tail: acc -> LDS bf16 (A@0, D@DOFF, row stride 528B) ----
#pragma unroll
    for (int mi = 0; mi < 2; ++mi) {
#pragma unroll
        for (int j = 0; j < 4; ++j) {
            int r = rh * 32 + mi * 16 + lk * 4 + j;
#pragma unroll
            for (int ni = 0; ni < 4; ++ni) {
                int c = cg * 64 + ni * 16 + lrow;
                *(unsigned short*)(lds + r * ROWB + c * 2) = f2bf(accA[mi][ni][j]);
                *(unsigned short*)(lds + DOFF + r * ROWB + c * 2) = f2bf(accD[mi][ni][j]);
            }
        }
    }
    __syncthreads();

    // ---- AD global write, coalesced from LDS (stores stay in flight) ----
    {
        const int r = tid >> 3, s8 = tid & 7;           // row 0..95, 32-el chunk
        const size_t gbase = (size_t)(mtile * 96 + r) * 256 + s8 * 32;
#pragma unroll
        for (int q = 0; q < 4; ++q) {
            svec8 va = *(const svec8*)(lds + r * ROWB + (s8 * 32 + q * 8) * 2);
            *(svec8*)(AD + gbase + q * 8) = va;
        }
#pragma unroll
        for (int q = 0; q < 4; ++q) {
            svec8 vd = *(const svec8*)(lds + DOFF + r * ROWB + (s8 * 32 + q * 8) * 2);
            *(svec8*)(AD + AD_HALF + gbase + q * 8) = vd;
        }
    }

    // ---- stats from LDS (no L2 round-trip) ----
    {
        float* red = (float*)(lds + REDOFF);
        if (tid < 512) {
            const int c = tid & 255;
            const int half = tid >> 8;
            const float bias = conv_b[c];
            float s1 = 0.f, s2 = 0.f;
            for (int g = half * 8; g < half * 8 + 8; ++g) {
                float a[6], d[6];
#pragma unroll
                for (int j = 0; j < 6; ++j) {
                    a[j] = bf2f(*(const unsigned short*)(lds + (g * 6 + j) * ROWB + c * 2));
                    d[j] = bf2f(*(const unsigned short*)(lds + DOFF + (g * 6 + j) * ROWB + c * 2));
                }
#pragma unroll
                for (int j = 0; j < 6; ++j) {
                    float aj = a[j] + bias;
#pragma unroll
                    for (int e = 0; e < 6; ++e) {
                        float h = fmaxf(aj + d[e], 0.f);
                        s1 += h;
                        s2 = fmaf(h, h, s2);
                    }
                }
            }
            red[half * 256 + c] = s1;
            red[512 + half * 256 + c] = s2;
        }
        __syncthreads();
        if (tid < 256) {
            atomicAdd(&stats[tid], red[tid] + red[256 + tid]);
            atomicAdd(&stats[256 + tid], red[512 + tid] + red[768 + tid]);
        }
    }
}

// ---------------- kernel 2: normalize + write output ----------------
// grid 2048 x 256: block handles 2 batches, XCD-matched to the gemm writer.
__global__ __launch_bounds__(256) void k_out(const unsigned short* __restrict__ AD,
                                             const float* __restrict__ conv_b,
                                             const float* __restrict__ gamma,
                                             const float* __restrict__ beta,
                                             const float* __restrict__ stats,
                                             float* __restrict__ out) {
    __shared__ float Al[6][260], Dl[6][260];
    __shared__ float sc[256], sh[256], bi[256];
    const int t = threadIdx.x;
    const int xcd = blockIdx.x & 7;
    const int tt = blockIdx.x >> 3;             // 0..255
    const int mt = xcd + 8 * (tt >> 3);         // mtile class match: mt%8 == xcd
    const int rbase = (tt & 7) * 2;             // batch-pair within mtile

    const float inv_n = 1.0f / (float)NTOT;
    float mean = stats[t] * inv_n;
    float var = fmaf(-mean, mean, stats[256 + t] * inv_n);
    float scale = gamma[t] * rsqrtf(var + 1e-5f);
    sc[t] = scale;
    sh[t] = fmaf(-mean, scale, beta[t]);
    bi[t] = conv_b[t];

#pragma unroll
    for (int u = 0; u < 2; ++u) {
        const int b = mt * 16 + rbase + u;
        const unsigned short* ga = AD + (size_t)b * 1536;
        const unsigned short* gd = AD + AD_HALF + (size_t)b * 1536;
        __syncthreads();   // protect Al/Dl overwrite (and first-iter sc publish)
#pragma unroll
        for (int i = 0; i < 6; ++i) {
            Al[i][t] = bf2f(ga[i * 256 + t]);
            Dl[i][t] = bf2f(gd[i * 256 + t]);
        }
        __syncthreads();
        float* ob = out + (size_t)b * 9216;
#pragma unroll
        for (int it = 0; it < 9; ++it) {
            int idx0 = it * 1024 + t * 4;
            fvec4 v;
#pragma unroll
            for (int q = 0; q < 4; ++q) {
                int idx = idx0 + q;
                int c = idx / 36;
                int r = idx - c * 36;
                int ii = r / 6;
                int j = r - ii * 6;
                int d = j - ii; if (d < 0) d += 6;
                float h = fmaxf(Al[j][c] + Dl[d][c] + bi[c], 0.f);
                v[q] = fmaf(h, sc[c], sh[c]);
            }
            __builtin_nontemporal_store(v, (fvec4*)(ob + idx0));
        }
    }
}

extern "C" void kernel_launch(void* const* d_in, const int* in_sizes, int n_in,
                              void* d_out, int out_size, void* d_ws, size_t ws_size,
                              hipStream_t stream) {
    const float* x      = (const float*)d_in[0];
    const float* conv_w = (const float*)d_in[1];
    const float* conv_b = (const float*)d_in[2];
    const float* gamma  = (const float*)d_in[3];
    const float* beta   = (const float*)d_in[4];
    float* out = (float*)d_out;

    char* ws = (char*)d_ws;
    unsigned short* wbf = (unsigned short*)ws;                       // 512 KB
    unsigned short* AD  = (unsigned short*)(ws + 524288);            // 25165824 B
    float* stats        = (float*)(ws + 524288 + 25165824);          // 2 KB

    k_pre<<<256, 256, 0, stream>>>(conv_w, wbf, stats);
    k_gemm_fused<<<256, 768, 0, stream>>>(x, wbf, conv_b, AD, stats);
    k_out<<<2048, 256, 0, stream>>>(AD, conv_b, gamma, beta, stats, out);
}

// Round 17
// 73.268 us; speedup vs baseline: 1.0247x; 1.0247x over previous
//
#include <hip/hip_runtime.h>

typedef __attribute__((ext_vector_type(8))) short svec8;
typedef __attribute__((ext_vector_type(4))) float fvec4;

#define NB    4096
#define NN    6
#define FF    512
#define CC    256
#define KFULL 1024
#define MROWS (NB*NN)                 // 24576
#define AD_HALF ((size_t)MROWS*CC)    // 6291456 elements
#define NTOT  (NB*NN*NN)              // 147456

// LDS map: Abuf0@0 Abuf1@12288 (12KB each) | Bbuf0@24576 Bbuf1@57344 (32KB each). total 90112.
#define ABUF_STRIDE 12288
#define BOFF        24576
#define BBUF_STRIDE 32768
#define LDS_BYTES   90112

#define GLOAD16(gp, lp) __builtin_amdgcn_global_load_lds(                      \
    (const __attribute__((address_space(1))) unsigned int*)(gp),               \
    (__attribute__((address_space(3))) unsigned int*)(lp), 16, 0, 0)

__device__ __forceinline__ unsigned short f2bf(float f) {
    unsigned u = __float_as_uint(f);
    u += 0x7FFFu + ((u >> 16) & 1u);   // round-to-nearest-even
    return (unsigned short)(u >> 16);
}
__device__ __forceinline__ float bf2f(unsigned short h) {
    return __uint_as_float(((unsigned)h) << 16);
}
__device__ __forceinline__ svec8 cvt8(fvec4 lo, fvec4 hi) {
    svec8 v;
    v[0] = (short)f2bf(lo[0]); v[1] = (short)f2bf(lo[1]);
    v[2] = (short)f2bf(lo[2]); v[3] = (short)f2bf(lo[3]);
    v[4] = (short)f2bf(hi[0]); v[5] = (short)f2bf(hi[1]);
    v[6] = (short)f2bf(hi[2]); v[7] = (short)f2bf(hi[3]);
    return v;
}

// ---------------- kernel 0: conv_w fp32->bf16 + zero stats ----------------
__global__ __launch_bounds__(256) void k_pre(const float* __restrict__ w,
                                             unsigned short* __restrict__ wbf,
                                             float* __restrict__ stats) {
    int g = blockIdx.x * 256 + threadIdx.x;   // grid 256 -> 65536 vec4 chunks
    fvec4 v = *(const fvec4*)(w + (size_t)g * 4);
    unsigned long long pk = (unsigned long long)f2bf(v[0])
                          | ((unsigned long long)f2bf(v[1]) << 16)
                          | ((unsigned long long)f2bf(v[2]) << 32)
                          | ((unsigned long long)f2bf(v[3]) << 48);
    *(unsigned long long*)(wbf + (size_t)g * 4) = pk;
    if (g < 512) stats[g] = 0.f;
}

// ---------------- kernel 1: GEMM both halves + fused stats (best: R11/R15) ----------------
// grid 256 x 768 thr (12 waves = 3/SIMD, 1 block/CU). Block owns rows
// [mtile*96,+96) = 16 b-groups. Pass s=0: A-half, s=1: D-half. Dbuf: per kt
// issue B(kt+1)->nxt + x(kt+1) regs before MFMA(kt), write A(kt+1) after.
// Wave wv: cg=wv&3 (64 cols), rh=wv>>2 (32 rows), acc[2][4] per pass.
// Tail: re-read own AD tile (L2-hot) -> stats atomics.
__global__ __launch_bounds__(768, 1) void k_gemm_fused(
        const float* __restrict__ x,
        const unsigned short* __restrict__ wbf,
        const float* __restrict__ conv_b,
        unsigned short* __restrict__ AD,
        float* __restrict__ stats) {
    __shared__ __align__(16) char lds[LDS_BYTES];
    const int tid = threadIdx.x;
    const int mtile = blockIdx.x;               // 0..255
    const int wv = tid >> 6;
    const int cg = wv & 3;                      // col-group: 64 cols
    const int rh = wv >> 2;                     // row-group: 32 rows

    // A staging: 768 16B-chunks, exactly one per thread. row 0..95, slot 0..7
    const int arow = tid >> 3, slot = tid & 7;
    const int a_off = arow * 128 + ((slot * 16) ^ ((arow & 7) << 4));

    // B staging: 2048 chunks; i=0,1 all threads, i=2 only tid<512
    int bxs[3], brow[3], bdoff[3];
#pragma unroll
    for (int i = 0; i < 3; ++i) {
        int ci = i * 768 + tid;
        brow[i] = ci >> 3;
        bxs[i] = ((ci & 7) ^ (brow[i] & 7)) << 3;
        bdoff[i] = i * 12288 + wv * 1024;       // wave-uniform base
    }
    const bool has_b2 = (tid < 512);

    // fragment LDS offsets
    const int l = tid & 63;
    const int lrow = l & 15;
    const int lk = l >> 4;
    int abase[2], bbase[2];
#pragma unroll
    for (int ks = 0; ks < 2; ++ks) {
        int xr = (ks * 64 + lk * 16) ^ ((lrow & 7) << 4);
        abase[ks] = (rh * 32 + lrow) * 128 + xr;
        bbase[ks] = BOFF + (cg * 64 + lrow) * 128 + xr;
    }

    const fvec4 vzero = {0.f, 0.f, 0.f, 0.f};
    fvec4 accA[2][4], accD[2][4];
#pragma unroll
    for (int mi = 0; mi < 2; ++mi)
#pragma unroll
        for (int ni = 0; ni < 4; ++ni) { accA[mi][ni] = vzero; accD[mi][ni] = vzero; }

#pragma unroll
    for (int s = 0; s < 2; ++s) {
        fvec4 (&acc)[2][4] = s ? accD : accA;

        // per-pass global A address (1 row-chunk per thread)
        int m0 = mtile * 96 + arow, b0 = m0 / 6, j0 = m0 - b0 * 6;
        const float* aptr = x + ((size_t)((b0 * 2 + s) * 6 + j0)) * FF + slot * 8;

        const unsigned short* bsrc[3];
#pragma unroll
        for (int i = 0; i < 3; ++i)
            bsrc[i] = wbf + (size_t)brow[i] * KFULL + s * FF + bxs[i];

        // ---- prologue: stage tile kt=0 into buf0 ----
        GLOAD16(bsrc[0], lds + BOFF + bdoff[0]);
        GLOAD16(bsrc[1], lds + BOFF + bdoff[1]);
        if (has_b2) GLOAD16(bsrc[2], lds + BOFF + bdoff[2]);
        {
            fvec4 lo = *(const fvec4*)aptr, hi = *(const fvec4*)(aptr + 4);
            *(svec8*)(lds + a_off) = cvt8(lo, hi);
        }
        __syncthreads();

#pragma unroll
        for (int kt = 0; kt < 8; ++kt) {
            const int cur = kt & 1, nxt = cur ^ 1;
            fvec4 nlo, nhi;
            // 1) issue next-tile loads BEFORE compute
            if (kt < 7) {
                GLOAD16(bsrc[0] + (kt + 1) * 64, lds + BOFF + nxt * BBUF_STRIDE + bdoff[0]);
                GLOAD16(bsrc[1] + (kt + 1) * 64, lds + BOFF + nxt * BBUF_STRIDE + bdoff[1]);
                if (has_b2)
                    GLOAD16(bsrc[2] + (kt + 1) * 64, lds + BOFF + nxt * BBUF_STRIDE + bdoff[2]);
                const float* p = aptr + (kt + 1) * 64;
                nlo = *(const fvec4*)p; nhi = *(const fvec4*)(p + 4);
            }
            // 2) MFMA on current buffers
#pragma unroll
            for (int ks = 0; ks < 2; ++ks) {
                svec8 af[2], bfr[4];
#pragma unroll
                for (int mi = 0; mi < 2; ++mi)
                    af[mi] = *(const svec8*)(lds + cur * ABUF_STRIDE + abase[ks] + mi * 2048);
#pragma unroll
                for (int ni = 0; ni < 4; ++ni)
                    bfr[ni] = *(const svec8*)(lds + cur * BBUF_STRIDE + bbase[ks] + ni * 2048);
#pragma unroll
                for (int mi = 0; mi < 2; ++mi)
#pragma unroll
                    for (int ni = 0; ni < 4; ++ni)
                        acc[mi][ni] = __builtin_amdgcn_mfma_f32_16x16x32_bf16(
                            af[mi], bfr[ni], acc[mi][ni], 0, 0, 0);
            }
            // 3) write next A tile (reg load covered by MFMA phase)
            if (kt < 7)
                *(svec8*)(lds + nxt * ABUF_STRIDE + a_off) = cvt8(nlo, nhi);
            __syncthreads();
        }

        // epilogue for this pass: C/D layout col=lane&15, row=(lane>>4)*4+reg
        unsigned short* op = AD + (size_t)s * AD_HALF;
#pragma unroll
        for (int mi = 0; mi < 2; ++mi) {
#pragma unroll
            for (int j = 0; j < 4; ++j) {
                int r = rh * 32 + mi * 16 + lk * 4 + j;
                size_t m = (size_t)(mtile * 96 + r);
#pragma unroll
                for (int ni = 0; ni < 4; ++ni) {
                    int c = cg * 64 + ni * 16 + lrow;
                    op[m * 256 + c] = f2bf(acc[mi][ni][j]);
                }
            }
        }
    }

    // ---- fused stats tail: re-read own tile (L2-hot), reduce, atomic ----
    asm volatile("s_waitcnt vmcnt(0)" ::: "memory");
    __syncthreads();   // all waves' AD stores drained to L2
    {
        float* red = (float*)lds;
        if (tid < 512) {
            const int c = tid & 255;
            const int half = tid >> 8;
            const float bias = conv_b[c];
            float s1 = 0.f, s2 = 0.f;
            for (int bb = 0; bb < 8; ++bb) {
                int bl = half * 8 + bb;
                size_t m0 = (size_t)(mtile * 96 + bl * 6);
                const unsigned short* ga = AD + m0 * 256 + c;
                const unsigned short* gd = AD + AD_HALF + m0 * 256 + c;
                float a[6], d[6];
#pragma unroll
                for (int j = 0; j < 6; ++j) { a[j] = bf2f(ga[j * 256]); d[j] = bf2f(gd[j * 256]); }
#pragma unroll
                for (int j = 0; j < 6; ++j) {
                    float aj = a[j] + bias;
#pragma unroll
                    for (int e = 0; e < 6; ++e) {
                        float h = fmaxf(aj + d[e], 0.f);
                        s1 += h;
                        s2 = fmaf(h, h, s2);
                    }
                }
            }
            red[half * 256 + c] = s1;
            red[512 + half * 256 + c] = s2;
        }
        __syncthreads();
        if (tid < 256) {
            atomicAdd(&stats[tid], red[tid] + red[256 + tid]);
            atomicAdd(&stats[256 + tid], red[512 + tid] + red[768 + tid]);
        }
    }
}

// ---------------- kernel 2: normalize + write output ----------------
// grid 2048 x 256: block handles 2 batches, XCD-matched to the gemm writer
// (gemm block mtile=b/16 ran on XCD mtile%8; we pick batches with matching
// XCD class so the AD re-read hits the local L2).
__global__ __launch_bounds__(256) void k_out(const unsigned short* __restrict__ AD,
                                             const float* __restrict__ conv_b,
                                             const float* __restrict__ gamma,
                                             const float* __restrict__ beta,
                                             const float* __restrict__ stats,
                                             float* __restrict__ out) {
    __shared__ float Al[6][260], Dl[6][260];
    __shared__ float sc[256], sh[256], bi[256];
    const int t = threadIdx.x;
    const int xcd = blockIdx.x & 7;
    const int tt = blockIdx.x >> 3;             // 0..255
    const int mt = xcd + 8 * (tt >> 3);         // mtile class match: mt%8 == xcd
    const int rbase = (tt & 7) * 2;             // batch-pair within mtile

    const float inv_n = 1.0f / (float)NTOT;
    float mean = stats[t] * inv_n;
    float var = fmaf(-mean, mean, stats[256 + t] * inv_n);
    float scale = gamma[t] * rsqrtf(var + 1e-5f);
    sc[t] = scale;
    sh[t] = fmaf(-mean, scale, beta[t]);
    bi[t] = conv_b[t];

#pragma unroll
    for (int u = 0; u < 2; ++u) {
        const int b = mt * 16 + rbase + u;
        const unsigned short* ga = AD + (size_t)b * 1536;
        const unsigned short* gd = AD + AD_HALF + (size_t)b * 1536;
        __syncthreads();   // protect Al/Dl overwrite (and first-iter sc publish)
#pragma unroll
        for (int i = 0; i < 6; ++i) {
            Al[i][t] = bf2f(ga[i * 256 + t]);
            Dl[i][t] = bf2f(gd[i * 256 + t]);
        }
        __syncthreads();
        float* ob = out + (size_t)b * 9216;
#pragma unroll
        for (int it = 0; it < 9; ++it) {
            int idx0 = it * 1024 + t * 4;
            fvec4 v;
#pragma unroll
            for (int q = 0; q < 4; ++q) {
                int idx = idx0 + q;
                int c = idx / 36;
                int r = idx - c * 36;
                int ii = r / 6;
                int j = r - ii * 6;
                int d = j - ii; if (d < 0) d += 6;
                float h = fmaxf(Al[j][c] + Dl[d][c] + bi[c], 0.f);
                v[q] = fmaf(h, sc[c], sh[c]);
            }
            __builtin_nontemporal_store(v, (fvec4*)(ob + idx0));
        }
    }
}

extern "C" void kernel_launch(void* const* d_in, const int* in_sizes, int n_in,
                              void* d_out, int out_size, void* d_ws, size_t ws_size,
                              hipStream_t stream) {
    const float* x      = (const float*)d_in[0];
    const float* conv_w = (const float*)d_in[1];
    const float* conv_b = (const float*)d_in[2];
    const float* gamma  = (const float*)d_in[3];
    const float* beta   = (const float*)d_in[4];
    float* out = (float*)d_out;

    char* ws = (char*)d_ws;
    unsigned short* wbf = (unsigned short*)ws;                       // 512 KB
    unsigned short* AD  = (unsigned short*)(ws + 524288);            // 25165824 B
    float* stats        = (float*)(ws + 524288 + 25165824);          // 2 KB

    k_pre<<<256, 256, 0, stream>>>(conv_w, wbf, stats);
    k_gemm_fused<<<256, 768, 0, stream>>>(x, wbf, conv_b, AD, stats);
    k_out<<<2048, 256, 0, stream>>>(AD, conv_b, gamma, beta, stats, out);
}